// Round 2
// baseline (1539.199 us; speedup 1.0000x reference)
//
#include <hip/hip_runtime.h>
#include <cmath>
#include <cfloat>
#include <climits>

#define NFEAT 20000
#define DDIM 256
#define KDIM 64
#define NSEG 313  // ceil(20000/64); last segment has 32 valid columns

// ---------------------------------------------------------------------------
// Shared post-dot z computation (must be bitwise-identical in K1 and K3).
// z = (ln10 + clamp(logp, log(1e-7), log(0.9999999)) + gumbel) / temp
// ---------------------------------------------------------------------------
__device__ __forceinline__ double z_post(double Lraw, float uu) {
  double L = fmin(fmax(Lraw, -16.118095650958320), -1.0000000500000034e-7);
  double g = -log(-log((double)uu));
  return (2.302585092994045684 + L + g) / 9.9999;
}

// Recompute z[d][n] from scratch: f64 dot (ascending k, fma chain) minus lseN.
__device__ __forceinline__ double compute_z(
    const float* __restrict__ u, const float* __restrict__ W,
    const float* __restrict__ unif, const double* __restrict__ lseN,
    int dd, int n) {
  double acc = 0.0;
  const float* ur = u + (size_t)n * KDIM;
#pragma unroll 8
  for (int k = 0; k < KDIM; ++k)
    acc = fma((double)ur[k], (double)W[k * DDIM + dd], acc);
  double Lraw = acc - lseN[n];
  return z_post(Lraw, unif[(size_t)dd * NFEAT + n]);
}

// ---------------------------------------------------------------------------
// K1: one block per 64-column segment. Thread d owns output row d for all 64
// n in the segment. Computes M[n,d] (f64 dot), block-reduces per-n softmax
// stats, stores lseN[n] = log sum_j exp(M[n,j]); computes z[d][n] on the fly
// and tracks per-(d,seg) max/argmax + logsumexp.
// ---------------------------------------------------------------------------
__global__ __launch_bounds__(256) void k_seg(
    const float* __restrict__ u, const float* __restrict__ W,
    const float* __restrict__ unif, double* __restrict__ lseN,
    double* __restrict__ segVal, double* __restrict__ segLse,
    int* __restrict__ segCol) {
  const int s = blockIdx.x;
  const int n0 = s * 64;
  const int nv = min(64, NFEAT - n0);
  const int d = threadIdx.x;
  const int lane = d & 63, w = d >> 6;

  __shared__ __align__(16) float ut[64 * 64];
  __shared__ double smax[4][8], ssum[4][8];

  for (int i = d; i < 64 * 64; i += 256) {
    int r = i >> 6;
    ut[i] = (r < nv) ? u[(size_t)(n0 + r) * KDIM + (i & 63)] : 0.f;
  }
  float wcol[64];
#pragma unroll
  for (int k = 0; k < KDIM; ++k) wcol[k] = W[k * DDIM + d];
  __syncthreads();

  double segm = -INFINITY;
  int segc = -1;
  double sm = -INFINITY, ss = 0.0;

  for (int b0 = 0; b0 < nv; b0 += 8) {
    double acc[8];
#pragma unroll
    for (int i = 0; i < 8; ++i) acc[i] = 0.0;
    const float* ur = &ut[b0 * 64];
    for (int k4 = 0; k4 < 16; ++k4) {
      const int kb = k4 * 4;
      const double w0 = (double)wcol[kb + 0], w1 = (double)wcol[kb + 1];
      const double w2 = (double)wcol[kb + 2], w3 = (double)wcol[kb + 3];
#pragma unroll
      for (int i = 0; i < 8; ++i) {
        const float4 uv = *(const float4*)&ur[i * 64 + kb];
        acc[i] = fma((double)uv.x, w0, acc[i]);
        acc[i] = fma((double)uv.y, w1, acc[i]);
        acc[i] = fma((double)uv.z, w2, acc[i]);
        acc[i] = fma((double)uv.w, w3, acc[i]);
      }
    }
    // block max per n
    double mloc[8];
#pragma unroll
    for (int i = 0; i < 8; ++i) mloc[i] = acc[i];
#pragma unroll
    for (int off = 1; off < 64; off <<= 1)
#pragma unroll
      for (int i = 0; i < 8; ++i)
        mloc[i] = fmax(mloc[i], __shfl_xor(mloc[i], off, 64));
    if (lane == 0)
#pragma unroll
      for (int i = 0; i < 8; ++i) smax[w][i] = mloc[i];
    __syncthreads();
    double mx[8];
#pragma unroll
    for (int i = 0; i < 8; ++i)
      mx[i] = fmax(fmax(smax[0][i], smax[1][i]), fmax(smax[2][i], smax[3][i]));
    // block sum of exp per n
    double sloc[8];
#pragma unroll
    for (int i = 0; i < 8; ++i) sloc[i] = exp(acc[i] - mx[i]);
#pragma unroll
    for (int off = 1; off < 64; off <<= 1)
#pragma unroll
      for (int i = 0; i < 8; ++i) sloc[i] += __shfl_xor(sloc[i], off, 64);
    if (lane == 0)
#pragma unroll
      for (int i = 0; i < 8; ++i) ssum[w][i] = sloc[i];
    __syncthreads();
#pragma unroll
    for (int i = 0; i < 8; ++i) {
      double tot = ssum[0][i] + ssum[1][i] + ssum[2][i] + ssum[3][i];
      double logZ = mx[i] + log(tot);
      int n = n0 + b0 + i;
      if (d == i + b0) lseN[n] = logZ;  // threads 0..nv-1 each write one n
      double zz = z_post(acc[i] - logZ, unif[(size_t)d * NFEAT + n]);
      if (zz > segm) { segm = zz; segc = n; }
      if (zz > sm) { ss = ss * exp(sm - zz) + 1.0; sm = zz; }
      else ss += exp(zz - sm);
    }
    __syncthreads();  // protect smax/ssum before next batch
  }
  segVal[(size_t)s * DDIM + d] = segm;
  segCol[(size_t)s * DDIM + d] = segc;
  segLse[(size_t)s * DDIM + d] = sm + log(ss);
}

// ---------------------------------------------------------------------------
// K2: logL[d] = log sum over segments of exp(segLse). 256 blocks x 64 lanes.
// ---------------------------------------------------------------------------
__global__ __launch_bounds__(64) void k_logL(const double* __restrict__ segLse,
                                             double* __restrict__ logL) {
  const int dd = blockIdx.x, lane = threadIdx.x;
  double v[5];
#pragma unroll
  for (int i = 0; i < 5; ++i) {
    int s = lane + i * 64;
    v[i] = (s < NSEG) ? segLse[(size_t)s * DDIM + dd] : -INFINITY;
  }
  double m = v[0];
#pragma unroll
  for (int i = 1; i < 5; ++i) m = fmax(m, v[i]);
#pragma unroll
  for (int off = 1; off < 64; off <<= 1) m = fmax(m, __shfl_xor(m, off, 64));
  double sacc = 0.0;
#pragma unroll
  for (int i = 0; i < 5; ++i)
    if (v[i] != -INFINITY) sacc += exp(v[i] - m);
#pragma unroll
  for (int off = 1; off < 64; off <<= 1) sacc += __shfl_xor(sacc, off, 64);
  if (lane == 0) logL[dd] = m + log(sacc);
}

// ---------------------------------------------------------------------------
// K3: greedy argmax with row/col suppression. Single wave; lane owns 4 rows.
// Lazy: rows whose best col was suppressed rescan stored segment maxima;
// stale segments are recomputed cooperatively by the whole wave.
// ---------------------------------------------------------------------------
__global__ __launch_bounds__(64) void k_greedy(
    const float* __restrict__ u, const float* __restrict__ W,
    const float* __restrict__ unif, const double* __restrict__ lseN,
    double* __restrict__ segVal, int* __restrict__ segCol,
    const double* __restrict__ logL, int* __restrict__ sel) {
  const int lane = threadIdx.x;
  __shared__ unsigned int supp[NFEAT / 32];  // 625
  __shared__ int selLds[DDIM];
  for (int i = lane; i < NFEAT / 32; i += 64) supp[i] = 0u;

  double key[4], lL[4];
  int col[4];
#pragma unroll
  for (int r = 0; r < 4; ++r) {
    const int dd = lane + 64 * r;
    double best = -INFINITY;
    int bc = INT_MAX;
    for (int s = 0; s < NSEG; ++s) {
      double v = segVal[(size_t)s * DDIM + dd];
      int c = segCol[(size_t)s * DDIM + dd];
      if (c >= 0 && (v > best || (v == best && c < bc))) { best = v; bc = c; }
    }
    lL[r] = logL[dd];
    key[r] = best - lL[r];
    col[r] = bc;
  }
  __syncthreads();

  for (int t = 0; t < DDIM; ++t) {
    double kv = key[0];
    int kd = lane;
#pragma unroll
    for (int r = 1; r < 4; ++r)
      if (key[r] > kv) { kv = key[r]; kd = lane + 64 * r; }
#pragma unroll
    for (int off = 32; off > 0; off >>= 1) {
      double ov = __shfl_xor(kv, off, 64);
      int od = __shfl_xor(kd, off, 64);
      if (ov > kv || (ov == kv && od < kd)) { kv = ov; kd = od; }
    }
    const int x = kd, rx = x >> 6, lx = x & 63;
    int cx = col[0];
    if (rx == 1) cx = col[1];
    else if (rx == 2) cx = col[2];
    else if (rx == 3) cx = col[3];
    const int y = __shfl(cx, lx, 64);
    if (lane == lx) {
      if (rx == 0) key[0] = -INFINITY;
      else if (rx == 1) key[1] = -INFINITY;
      else if (rx == 2) key[2] = -INFINITY;
      else key[3] = -INFINITY;
    }
    if (lane == 0) {
      selLds[x] = y;
      supp[y >> 5] |= (1u << (y & 31));
    }
    __syncthreads();

#pragma unroll 1
    for (int r = 0; r < 4; ++r) {
      bool need = (col[r] == y) && (key[r] != -INFINITY);
      unsigned long long m0 = __ballot(need);
      while (m0) {
        int src = __ffsll(m0) - 1;
        m0 &= m0 - 1;
        const int dd2 = src + 64 * r;
        // phase 1: distributed scan of stored maxima; collect stale segs
        double pbv = -INFINITY;
        int pbc = INT_MAX;
        int stale[5];
        int scnt = 0;
#pragma unroll 1
        for (int i = 0; i < 5; ++i) {
          int s2 = lane + i * 64;
          if (s2 < NSEG) {
            double v = segVal[(size_t)s2 * DDIM + dd2];
            int c = segCol[(size_t)s2 * DDIM + dd2];
            if (c >= 0) {
              if ((supp[c >> 5] >> (c & 31)) & 1u) stale[scnt++] = s2;
              else if (v > pbv || (v == pbv && c < pbc)) { pbv = v; pbc = c; }
            }
          }
        }
        // phase 2: cooperative recompute of stale segments
        unsigned long long sm2 = __ballot(scnt > 0);
        while (sm2) {
          int src2 = __ffsll(sm2) - 1;
          int cand = (scnt > 0) ? stale[scnt - 1] : 0;
          int s2 = __shfl(cand, src2, 64);
          if (lane == src2) scnt--;
          int cc = s2 * 64 + lane;
          double zv = -INFINITY;
          if (cc < NFEAT && !((supp[cc >> 5] >> (cc & 31)) & 1u))
            zv = compute_z(u, W, unif, lseN, dd2, cc);
          int zc = (zv == -INFINITY) ? INT_MAX : cc;
#pragma unroll
          for (int off = 32; off > 0; off >>= 1) {
            double ov = __shfl_xor(zv, off, 64);
            int oc = __shfl_xor(zc, off, 64);
            if (ov > zv || (ov == zv && oc < zc)) { zv = ov; zc = oc; }
          }
          if (lane == 0) {
            segVal[(size_t)s2 * DDIM + dd2] = zv;
            segCol[(size_t)s2 * DDIM + dd2] = (zc == INT_MAX) ? -1 : zc;
          }
          if (lane == src2 && zc != INT_MAX) {
            if (zv > pbv || (zv == pbv && zc < pbc)) { pbv = zv; pbc = zc; }
          }
          sm2 = __ballot(scnt > 0);
        }
        // phase 3: reduce partial bests across lanes
#pragma unroll
        for (int off = 32; off > 0; off >>= 1) {
          double ov = __shfl_xor(pbv, off, 64);
          int oc = __shfl_xor(pbc, off, 64);
          if (ov > pbv || (ov == pbv && oc < pbc)) { pbv = ov; pbc = oc; }
        }
        if (lane == src) { key[r] = pbv - lL[r]; col[r] = pbc; }
      }
    }
    __syncthreads();
  }
#pragma unroll
  for (int r = 0; r < 4; ++r) sel[lane + 64 * r] = selLds[lane + 64 * r];
}

// ---------------------------------------------------------------------------
// K4: Y[b,d] = X[b, sel[d]] for rows b = 1..4095. sel lives in out row 0
// (int bits), untouched here.
// ---------------------------------------------------------------------------
__global__ __launch_bounds__(256) void k_gather(const float* __restrict__ X,
                                                float* out) {
  const int dd = threadIdx.x;
  const size_t b = (size_t)blockIdx.x + 1;
  const int y = __float_as_int(out[dd]);
  out[b * DDIM + dd] = X[b * NFEAT + y];
}

// K5: row 0 (reads sel from its own slot, then overwrites it).
__global__ __launch_bounds__(256) void k_row0(const float* __restrict__ X,
                                              float* out) {
  const int dd = threadIdx.x;
  const int y = __float_as_int(out[dd]);
  const float v = X[y];  // b = 0
  out[dd] = v;
}

extern "C" void kernel_launch(void* const* d_in, const int* in_sizes, int n_in,
                              void* d_out, int out_size, void* d_ws,
                              size_t ws_size, hipStream_t stream) {
  (void)in_sizes; (void)n_in; (void)d_ws; (void)ws_size; (void)out_size;
  const float* X = (const float*)d_in[0];
  const float* u = (const float*)d_in[1];
  const float* W = (const float*)d_in[2];
  const float* unif = (const float*)d_in[3];

  // Scratch lives inside d_out (4 MB): rows >= 1 are dead until k_gather.
  char* ob = (char*)d_out;
  int* sel = (int*)ob;                          // [0, 1024)
  double* lseN = (double*)(ob + 1024);          // [1024, 161024)
  double* segVal = (double*)(ob + 161024);      // [161024, 802048)
  double* segLse = (double*)(ob + 802048);      // [802048, 1443072)
  int* segCol = (int*)(ob + 1443072);           // [1443072, 1763584)
  double* logL = (double*)(ob + 1763584);       // [1763584, 1765632)

  k_seg<<<NSEG, 256, 0, stream>>>(u, W, unif, lseN, segVal, segLse, segCol);
  k_logL<<<DDIM, 64, 0, stream>>>(segLse, logL);
  k_greedy<<<1, 64, 0, stream>>>(u, W, unif, lseN, segVal, segCol, logL, sel);
  k_gather<<<4095, 256, 0, stream>>>(X, (float*)d_out);
  k_row0<<<1, 256, 0, stream>>>(X, (float*)d_out);
}

// Round 3
// 676.935 us; speedup vs baseline: 2.2738x; 2.2738x over previous
//
#include <hip/hip_runtime.h>
#include <cmath>
#include <cfloat>
#include <climits>

#define NFEAT 20000
#define DDIM 256
#define KDIM 64
#define NSEG 313  // ceil(20000/64); last segment has 32 valid columns
#define SEGP 320  // padded leading dim for [d][s] arrays

// ---------------------------------------------------------------------------
// Shared post-dot z computation (bitwise-identical in k_seg and repair path).
// z = (ln10 + clamp(logp, log(1e-7), log(0.9999999)) + gumbel) / temp
// ---------------------------------------------------------------------------
__device__ __forceinline__ double z_post(double Lraw, float uu) {
  double L = fmin(fmax(Lraw, -16.118095650958320), -1.0000000500000034e-7);
  double g = -log(-log((double)uu));
  return (2.302585092994045684 + L + g) / 9.9999;
}

// Recompute z[d][n] from scratch: f64 dot (ascending k, fma chain) minus lseN.
__device__ __forceinline__ double compute_z(
    const float* __restrict__ u, const float* __restrict__ W,
    const float* __restrict__ unif, const double* __restrict__ lseN,
    int dd, int n) {
  double acc = 0.0;
  const float* ur = u + (size_t)n * KDIM;
#pragma unroll 8
  for (int k = 0; k < KDIM; ++k)
    acc = fma((double)ur[k], (double)W[k * DDIM + dd], acc);
  double Lraw = acc - lseN[n];
  return z_post(Lraw, unif[(size_t)dd * NFEAT + n]);
}

// ---------------------------------------------------------------------------
// K1: one block per 64-column segment. Thread d owns output row d.
// unif staged through LDS (coalesced global reads). No softmax max-shift
// (|M| small => exp safe). Writes segVal/segSum/segCol in [d][s] layout.
// ---------------------------------------------------------------------------
__global__ __launch_bounds__(256) void k_seg(
    const float* __restrict__ u, const float* __restrict__ W,
    const float* __restrict__ unif, double* __restrict__ lseN,
    double* __restrict__ segVal, double* __restrict__ segSum,
    int* __restrict__ segCol) {
  const int s = blockIdx.x;
  const int n0 = s * 64;
  const int nv = min(64, NFEAT - n0);
  const int d = threadIdx.x;
  const int lane = d & 63, w = d >> 6;

  __shared__ __align__(16) float ut[64 * 64];   // u tile [n_loc][k], 16 KB
  __shared__ float unT[32 * 256];               // unif half-tile [n_loc][d], 32 KB
  __shared__ double ssum[4][8];
  __shared__ double logZs[8];

  for (int i = d; i < 64 * 64; i += 256) {
    int r = i >> 6;
    ut[i] = (r < nv) ? u[(size_t)(n0 + r) * KDIM + (i & 63)] : 0.f;
  }
  float wcol[64];
#pragma unroll
  for (int k = 0; k < KDIM; ++k) wcol[k] = W[k * DDIM + d];

  double ssl = 0.0;
  double segm = -INFINITY;
  int segc = -1;

  for (int half = 0; half < 2; ++half) {
    const int hn0 = half * 32;
    if (hn0 >= nv) break;
    const int hnv = min(32, nv - hn0);
    __syncthreads();  // ut visible (half 0) / prior half's unT readers done
    // stage unif half-tile: thread d reads its own row (contiguous 128 B)
    for (int q = 0; q < hnv; q += 4) {
      const float4 t =
          *(const float4*)(unif + (size_t)d * NFEAT + n0 + hn0 + q);
      unT[(q + 0) * 256 + d] = t.x;
      unT[(q + 1) * 256 + d] = t.y;
      unT[(q + 2) * 256 + d] = t.z;
      unT[(q + 3) * 256 + d] = t.w;
    }
    __syncthreads();

    for (int b0 = hn0; b0 < hn0 + hnv; b0 += 8) {
      double acc[8];
#pragma unroll
      for (int i = 0; i < 8; ++i) acc[i] = 0.0;
#pragma unroll
      for (int k4 = 0; k4 < 16; ++k4) {
        const int kb = k4 * 4;
        const double w0 = (double)wcol[kb + 0], w1 = (double)wcol[kb + 1];
        const double w2 = (double)wcol[kb + 2], w3 = (double)wcol[kb + 3];
#pragma unroll
        for (int i = 0; i < 8; ++i) {
          const float4 uv = *(const float4*)&ut[(b0 + i) * 64 + kb];
          acc[i] = fma((double)uv.x, w0, acc[i]);
          acc[i] = fma((double)uv.y, w1, acc[i]);
          acc[i] = fma((double)uv.z, w2, acc[i]);
          acc[i] = fma((double)uv.w, w3, acc[i]);
        }
      }
      // softmax denominator over d (no max-shift; |acc| <= ~3)
      double sl[8];
#pragma unroll
      for (int i = 0; i < 8; ++i) sl[i] = exp(acc[i]);
#pragma unroll
      for (int off = 1; off < 64; off <<= 1)
#pragma unroll
        for (int i = 0; i < 8; ++i) sl[i] += __shfl_xor(sl[i], off, 64);
      if (lane == 0)
#pragma unroll
        for (int i = 0; i < 8; ++i) ssum[w][i] = sl[i];
      __syncthreads();
      if (d < 8) {
        double tot = ssum[0][d] + ssum[1][d] + ssum[2][d] + ssum[3][d];
        double lz = log(tot);
        logZs[d] = lz;
        lseN[n0 + b0 + d] = lz;
      }
      __syncthreads();
#pragma unroll 2
      for (int i = 0; i < 8; ++i) {
        const int n = n0 + b0 + i;
        const double zz =
            z_post(acc[i] - logZs[i], unT[(b0 + i - hn0) * 256 + d]);
        ssl += exp(zz);
        if (zz > segm) { segm = zz; segc = n; }
      }
      __syncthreads();  // protect ssum/logZs before next batch
    }
  }
  segVal[(size_t)d * SEGP + s] = segm;
  segCol[(size_t)d * SEGP + s] = segc;
  segSum[(size_t)d * SEGP + s] = ssl;
}

// ---------------------------------------------------------------------------
// K2: per row d: logL[d] = log(sum_s segSum), plus global row best/argmax.
// 256 blocks x 64 lanes, coalesced over the [d][s] layout.
// ---------------------------------------------------------------------------
__global__ __launch_bounds__(64) void k_rowstat(
    const double* __restrict__ segVal, const double* __restrict__ segSum,
    const int* __restrict__ segCol, double* __restrict__ logL,
    double* __restrict__ bestKey, int* __restrict__ bestCol) {
  const int dd = blockIdx.x, lane = threadIdx.x;
  double sum = 0.0, bv = -INFINITY;
  int bc = INT_MAX;
  for (int s = lane; s < NSEG; s += 64) {
    sum += segSum[(size_t)dd * SEGP + s];
    double v = segVal[(size_t)dd * SEGP + s];
    int c = segCol[(size_t)dd * SEGP + s];
    if (c >= 0 && (v > bv || (v == bv && c < bc))) { bv = v; bc = c; }
  }
#pragma unroll
  for (int off = 32; off > 0; off >>= 1) {
    sum += __shfl_xor(sum, off, 64);
    double ov = __shfl_xor(bv, off, 64);
    int oc = __shfl_xor(bc, off, 64);
    if (ov > bv || (ov == bv && oc < bc)) { bv = ov; bc = oc; }
  }
  if (lane == 0) {
    double lL = log(sum);
    logL[dd] = lL;
    bestKey[dd] = bv - lL;
    bestCol[dd] = bc;
  }
}

// ---------------------------------------------------------------------------
// K3: batched lazy greedy. Rank-sort 256 rows by key, then commit in sorted
// order 64 at a time; conflicts (suppressed/dup col) trigger wave-parallel
// repair + sorted re-insertion. Expected conflicts ~3 total.
// ---------------------------------------------------------------------------
__global__ __launch_bounds__(64) void k_greedy(
    const float* __restrict__ u, const float* __restrict__ W,
    const float* __restrict__ unif, const double* __restrict__ lseN,
    double* __restrict__ segVal, int* __restrict__ segCol,
    const double* __restrict__ logL, const double* __restrict__ bestKey,
    const int* __restrict__ bestCol, int* __restrict__ sel) {
  const int lane = threadIdx.x;
  __shared__ double kk[DDIM], sk[DDIM];
  __shared__ int sr[DDIM], sc[DDIM], selL[DDIM];
  __shared__ unsigned int supp[NFEAT / 32];
  for (int i = lane; i < NFEAT / 32; i += 64) supp[i] = 0u;

  double myk[4];
  int myc[4];
#pragma unroll
  for (int i = 0; i < 4; ++i) {
    int dd = lane + 64 * i;
    myk[i] = bestKey[dd];
    myc[i] = bestCol[dd];
    kk[dd] = myk[i];
  }
  __syncthreads();
  // rank sort (descending key, tie -> smaller row)
#pragma unroll
  for (int i = 0; i < 4; ++i) {
    int dd = lane + 64 * i;
    int rk = 0;
#pragma unroll 4
    for (int j = 0; j < DDIM; ++j) {
      double kj = kk[j];
      if (kj > myk[i] || (kj == myk[i] && j < dd)) ++rk;
    }
    sk[rk] = myk[i];
    sr[rk] = dd;
    sc[rk] = myc[i];
  }
  __syncthreads();

  int pos = 0;
  while (pos < DDIM) {
    const int p = pos + lane;
    const bool valid = p < DDIM;
    double kcur = 0.0;
    int r = -1, c = -1000000 - lane;  // unique negatives: no accidental dups
    if (valid) { kcur = sk[p]; r = sr[p]; c = sc[p]; }
    bool conf = !valid;
    if (valid) conf = (supp[c >> 5] >> (c & 31)) & 1u;
    bool dup = false;
#pragma unroll
    for (int j = 0; j < 63; ++j) {
      int cj = __shfl(c, j, 64);
      if (j < lane && cj == c) dup = true;
    }
    if (valid && dup) conf = true;
    unsigned long long bm = __ballot(conf);
    int fc = bm ? (__ffsll(bm) - 1) : 64;
    if (lane < fc) {
      selL[r] = c;
      atomicOr(&supp[c >> 5], 1u << (c & 31));
    }
    __syncthreads();
    pos += fc;
    if (fc < 64 && pos < DDIM) {
      const int rr = sr[pos];
      // wave-parallel repair of row rr
      double pbv = -INFINITY;
      int pbc = INT_MAX;
      int stale[5];
      int scnt = 0;
#pragma unroll
      for (int i2 = 0; i2 < 5; ++i2) {
        int s2 = lane + 64 * i2;
        if (s2 < NSEG) {
          double v = segVal[(size_t)rr * SEGP + s2];
          int cc = segCol[(size_t)rr * SEGP + s2];
          if (cc >= 0) {
            if ((supp[cc >> 5] >> (cc & 31)) & 1u) stale[scnt++] = s2;
            else if (v > pbv || (v == pbv && cc < pbc)) { pbv = v; pbc = cc; }
          }
        }
      }
      unsigned long long sm2 = __ballot(scnt > 0);
      while (sm2) {
        int src = __ffsll(sm2) - 1;
        int cand = (scnt > 0) ? stale[scnt - 1] : 0;
        int s2 = __shfl(cand, src, 64);
        if (lane == src) --scnt;
        int ccol = s2 * 64 + lane;
        double zv = -INFINITY;
        if (ccol < NFEAT && !((supp[ccol >> 5] >> (ccol & 31)) & 1u))
          zv = compute_z(u, W, unif, lseN, rr, ccol);
        int zc = (zv == -INFINITY) ? INT_MAX : ccol;
#pragma unroll
        for (int off = 32; off > 0; off >>= 1) {
          double ov = __shfl_xor(zv, off, 64);
          int oc = __shfl_xor(zc, off, 64);
          if (ov > zv || (ov == zv && oc < zc)) { zv = ov; zc = oc; }
        }
        if (lane == 0) {
          segVal[(size_t)rr * SEGP + s2] = (zc == INT_MAX) ? -INFINITY : zv;
          segCol[(size_t)rr * SEGP + s2] = (zc == INT_MAX) ? -1 : zc;
        }
        if (zc != INT_MAX && (zv > pbv || (zv == pbv && zc < pbc))) {
          pbv = zv;
          pbc = zc;
        }
        sm2 = __ballot(scnt > 0);
      }
#pragma unroll
      for (int off = 32; off > 0; off >>= 1) {
        double ov = __shfl_xor(pbv, off, 64);
        int oc = __shfl_xor(pbc, off, 64);
        if (ov > pbv || (ov == pbv && oc < pbc)) { pbv = ov; pbc = oc; }
      }
      const double knew = pbv - logL[rr];
      const int cn = pbc;
      // count entries that must stay ahead of the repaired one
      int cnt = 0;
      for (int q = pos + 1 + lane; q < DDIM; q += 64) {
        double kq = sk[q];
        int rq = sr[q];
        if (kq > knew || (kq == knew && rq < rr)) ++cnt;
      }
#pragma unroll
      for (int off = 32; off > 0; off >>= 1) cnt += __shfl_xor(cnt, off, 64);
      // shift entries pos+1 .. pos+cnt left by one, insert at pos+cnt
      for (int q0 = pos + 1; q0 <= pos + cnt; q0 += 64) {
        int q = q0 + lane;
        double tk = 0.0;
        int tr = 0, tc = 0;
        bool v2 = q <= pos + cnt;
        if (v2) { tk = sk[q]; tr = sr[q]; tc = sc[q]; }
        __syncthreads();
        if (v2) { sk[q - 1] = tk; sr[q - 1] = tr; sc[q - 1] = tc; }
        __syncthreads();
      }
      if (lane == 0) { sk[pos + cnt] = knew; sr[pos + cnt] = rr; sc[pos + cnt] = cn; }
      __syncthreads();
    }
  }
#pragma unroll
  for (int i = 0; i < 4; ++i) sel[lane + 64 * i] = selL[lane + 64 * i];
}

// ---------------------------------------------------------------------------
// K4: Y[b,d] = X[b, sel[d]] for rows b = 1..4095 (sel in out row 0).
// ---------------------------------------------------------------------------
__global__ __launch_bounds__(256) void k_gather(const float* __restrict__ X,
                                                float* out) {
  const int dd = threadIdx.x;
  const size_t b = (size_t)blockIdx.x + 1;
  const int y = __float_as_int(out[dd]);
  out[b * DDIM + dd] = X[b * NFEAT + y];
}

// K5: row 0 (reads sel from its own slot, then overwrites it).
__global__ __launch_bounds__(256) void k_row0(const float* __restrict__ X,
                                              float* out) {
  const int dd = threadIdx.x;
  const int y = __float_as_int(out[dd]);
  const float v = X[y];
  out[dd] = v;
}

extern "C" void kernel_launch(void* const* d_in, const int* in_sizes, int n_in,
                              void* d_out, int out_size, void* d_ws,
                              size_t ws_size, hipStream_t stream) {
  (void)in_sizes; (void)n_in; (void)d_ws; (void)ws_size; (void)out_size;
  const float* X = (const float*)d_in[0];
  const float* u = (const float*)d_in[1];
  const float* W = (const float*)d_in[2];
  const float* unif = (const float*)d_in[3];

  // Scratch lives inside d_out (4 MB): rows >= 1 are dead until k_gather.
  char* ob = (char*)d_out;
  int* sel = (int*)ob;                       // [0, 1024)
  double* lseN = (double*)(ob + 1024);       // 160000 B
  double* logL = (double*)(ob + 161024);     // 2048 B
  double* bestKey = (double*)(ob + 163072);  // 2048 B
  int* bestCol = (int*)(ob + 165120);        // 1024 B
  double* segVal = (double*)(ob + 166144);   // 256*320*8 = 655360 B
  double* segSum = (double*)(ob + 821504);   // 655360 B
  int* segCol = (int*)(ob + 1476864);        // 327680 B -> ends 1804544

  k_seg<<<NSEG, 256, 0, stream>>>(u, W, unif, lseN, segVal, segSum, segCol);
  k_rowstat<<<DDIM, 64, 0, stream>>>(segVal, segSum, segCol, logL, bestKey,
                                     bestCol);
  k_greedy<<<1, 64, 0, stream>>>(u, W, unif, lseN, segVal, segCol, logL,
                                 bestKey, bestCol, sel);
  k_gather<<<4095, 256, 0, stream>>>(X, (float*)d_out);
  k_row0<<<1, 256, 0, stream>>>(X, (float*)d_out);
}